// Round 4
// baseline (1341.168 us; speedup 1.0000x reference)
//
#include <hip/hip_runtime.h>
#include <hip/hip_bf16.h>

typedef unsigned short u16;
using bf16_t = __hip_bfloat16;

__device__ __forceinline__ float b2f(u16 u) {
    return __uint_as_float((unsigned int)u << 16);
}
__device__ __forceinline__ u16 f2b(float f) {
    bf16_t h = __float2bfloat16(f);
    union { bf16_t h; u16 u; } cv; cv.h = h; return cv.u;
}
// Dual-dtype loads for EXTERNAL inputs (fp32 or bf16, chosen at runtime).
__device__ __forceinline__ float ldv(const void* p, size_t i, int f32) {
    return f32 ? ((const float*)p)[i] : b2f(((const u16*)p)[i]);
}
__device__ __forceinline__ float4 ld4(const void* p, size_t i, int f32) {
    if (f32) return *reinterpret_cast<const float4*>((const float*)p + i);
    const ushort4 u = *reinterpret_cast<const ushort4*>((const u16*)p + i);
    float4 f; f.x = b2f(u.x); f.y = b2f(u.y); f.z = b2f(u.z); f.w = b2f(u.w);
    return f;
}

// ---------------------------------------------------------------------------
// Input-dtype detector: even u16 indices of x. bf16 buffer -> plausible bf16
// exponents for N(0,1); fp32 buffer -> low-half mantissa garbage.
// flag[0] = 1 means fp32 inputs AND fp32 output.
// ---------------------------------------------------------------------------
__global__ void detect_kernel(const void* __restrict__ x, int* __restrict__ flag)
{
    const int t = threadIdx.x;             // 64 threads
    const u16 h = ((const u16*)x)[2 * t];
    const int e = (h >> 7) & 0xFF;
    const int plaus = (e >= 112 && e <= 133) ? 1 : 0;
    const unsigned long long m = __ballot(plaus);
    if (t == 0) flag[0] = (__popcll(m) < 32) ? 1 : 0;
}

// ---------------------------------------------------------------------------
// GEMM: O[rows x Nc] = A[rows x 256] @ B[256 x Nc]; fp32 accumulate.
// 64x64 tile, BK=64, 256 threads, 4x4 micro-tile.
// MODE 0: O0(bf16) = A@B          (q; A=x external-dual)
// MODE 1: Nc=512; cols<256 -> O0 = A@B + pos_enc (k chunk, LOCAL rows);
//                 cols>=256 -> O1(bf16) = A@B (v, GLOBAL rows). A=x at row_base.
// MODE 2: out = A@B + bias; A=y INTERNAL bf16; store fp32 (flag) or bf16.
// ---------------------------------------------------------------------------
template<int MODE>
__global__ __launch_bounds__(256)
void gemm_k256(const void* __restrict__ A, const void* __restrict__ Bw,
               u16* __restrict__ O0, u16* __restrict__ O1,
               const void* __restrict__ extra, int Ncols, int row_base,
               const int* __restrict__ flagp)
{
    const int f32 = *flagp;
    __shared__ float As[64][64];   // As[k][m]
    __shared__ float Bs[64][64];   // Bs[k][n]
    const int tid  = threadIdx.x;
    const int row0 = blockIdx.y * 64;
    const int col0 = blockIdx.x * 64;

    float acc[4][4] = {};

    const int lr  = tid >> 2;
    const int lkq = tid & 3;
    const int bkr = tid >> 4;
    const int bc4 = tid & 15;
    const int tr  = (tid >> 4) * 4;
    const int tc  = (tid & 15) * 4;

    for (int k0 = 0; k0 < 256; k0 += 64) {
        #pragma unroll
        for (int j = 0; j < 4; ++j) {
            const int kk = lkq * 4 + j * 16;
            float4 f;
            if (MODE == 2) {   // internal bf16 A
                const ushort4 u = *reinterpret_cast<const ushort4*>(
                    (const u16*)A + (size_t)(row0 + lr) * 256 + k0 + kk);
                f.x = b2f(u.x); f.y = b2f(u.y); f.z = b2f(u.z); f.w = b2f(u.w);
            } else {           // external x
                f = ld4(A, (size_t)(row_base + row0 + lr) * 256 + k0 + kk, f32);
            }
            As[kk+0][lr] = f.x;
            As[kk+1][lr] = f.y;
            As[kk+2][lr] = f.z;
            As[kk+3][lr] = f.w;
        }
        #pragma unroll
        for (int j = 0; j < 4; ++j) {
            const int kk = bkr + j * 16;
            const float4 f = ld4(Bw, (size_t)(k0 + kk) * Ncols + col0 + bc4 * 4, f32);
            *reinterpret_cast<float4*>(&Bs[kk][bc4 * 4]) = f;
        }
        __syncthreads();
        #pragma unroll
        for (int k = 0; k < 64; ++k) {
            const float4 a = *reinterpret_cast<const float4*>(&As[k][tr]);
            const float4 b = *reinterpret_cast<const float4*>(&Bs[k][tc]);
            acc[0][0] = fmaf(a.x,b.x,acc[0][0]); acc[0][1] = fmaf(a.x,b.y,acc[0][1]);
            acc[0][2] = fmaf(a.x,b.z,acc[0][2]); acc[0][3] = fmaf(a.x,b.w,acc[0][3]);
            acc[1][0] = fmaf(a.y,b.x,acc[1][0]); acc[1][1] = fmaf(a.y,b.y,acc[1][1]);
            acc[1][2] = fmaf(a.y,b.z,acc[1][2]); acc[1][3] = fmaf(a.y,b.w,acc[1][3]);
            acc[2][0] = fmaf(a.z,b.x,acc[2][0]); acc[2][1] = fmaf(a.z,b.y,acc[2][1]);
            acc[2][2] = fmaf(a.z,b.z,acc[2][2]); acc[2][3] = fmaf(a.z,b.w,acc[2][3]);
            acc[3][0] = fmaf(a.w,b.x,acc[3][0]); acc[3][1] = fmaf(a.w,b.y,acc[3][1]);
            acc[3][2] = fmaf(a.w,b.z,acc[3][2]); acc[3][3] = fmaf(a.w,b.w,acc[3][3]);
        }
        __syncthreads();
    }

    #pragma unroll
    for (int i = 0; i < 4; ++i) {
        const size_t r = (size_t)row0 + tr + i;      // local row
        if (MODE == 0) {
            ushort4 o;
            o.x = f2b(acc[i][0]); o.y = f2b(acc[i][1]);
            o.z = f2b(acc[i][2]); o.w = f2b(acc[i][3]);
            *reinterpret_cast<ushort4*>(&O0[r * 256 + col0 + tc]) = o;
        } else if (MODE == 1) {
            const size_t g = (size_t)row_base + r;   // global row
            if (col0 < 256) {
                const size_t n = g & 4095;
                ushort4 o;
                o.x = f2b(acc[i][0] + ldv(extra, n * 256 + col0 + tc + 0, f32));
                o.y = f2b(acc[i][1] + ldv(extra, n * 256 + col0 + tc + 1, f32));
                o.z = f2b(acc[i][2] + ldv(extra, n * 256 + col0 + tc + 2, f32));
                o.w = f2b(acc[i][3] + ldv(extra, n * 256 + col0 + tc + 3, f32));
                *reinterpret_cast<ushort4*>(&O0[r * 256 + col0 + tc]) = o;
            } else {
                ushort4 o;
                o.x = f2b(acc[i][0]); o.y = f2b(acc[i][1]);
                o.z = f2b(acc[i][2]); o.w = f2b(acc[i][3]);
                *reinterpret_cast<ushort4*>(&O1[g * 256 + (col0 - 256) + tc]) = o;
            }
        } else {
            // MODE 2: final output — dtype follows detected input dtype.
            float4 o;
            o.x = acc[i][0] + ldv(extra, col0 + tc + 0, f32);
            o.y = acc[i][1] + ldv(extra, col0 + tc + 1, f32);
            o.z = acc[i][2] + ldv(extra, col0 + tc + 2, f32);
            o.w = acc[i][3] + ldv(extra, col0 + tc + 3, f32);
            if (f32) {
                *reinterpret_cast<float4*>((float*)O0 + r * 256 + col0 + tc) = o;
            } else {
                ushort4 ob;
                ob.x = f2b(o.x); ob.y = f2b(o.y); ob.z = f2b(o.z); ob.w = f2b(o.w);
                *reinterpret_cast<ushort4*>(O0 + r * 256 + col0 + tc) = ob;
            }
        }
    }
}

// ---------------------------------------------------------------------------
// Focus: t=(relu(t)+eps)/softplus(p); t := t^3 * ||t||/||t^3||.
// In-place bf16, fp32 math. 4 rows/block.
// ---------------------------------------------------------------------------
__global__ __launch_bounds__(256)
void focus_kernel(u16* __restrict__ buf, const void* __restrict__ scale_param,
                  const int* __restrict__ flagp)
{
    const int f32 = *flagp;
    __shared__ float ssc[256];
    const int tid = threadIdx.x;
    {
        const float p = ldv(scale_param, tid, f32);
        ssc[tid] = (p > 20.f) ? p : log1pf(expf(p));   // softplus
    }
    __syncthreads();
    const int lane = tid & 63;
    const int wv   = tid >> 6;
    const size_t row = (size_t)blockIdx.x * 4 + wv;
    u16* t = buf + row * 256;
    float tv[4]; float s2 = 0.f, s6 = 0.f;
    #pragma unroll
    for (int i = 0; i < 4; ++i) {
        const int c = lane + i * 64;
        float x = b2f(t[c]);
        x = fmaxf(x, 0.f) + 1e-6f;
        x = x / ssc[c];
        tv[i] = x;
        const float x2 = x * x;
        s2 += x2;
        const float x3 = x2 * x;
        s6 += x3 * x3;
    }
    #pragma unroll
    for (int off = 32; off > 0; off >>= 1) {
        s2 += __shfl_xor(s2, off);
        s6 += __shfl_xor(s6, off);
    }
    const float ratio = sqrtf(s2 / s6);
    #pragma unroll
    for (int i = 0; i < 4; ++i) {
        const int c = lane + i * 64;
        const float x = tv[i];
        t[c] = f2b(x * x * x * ratio);
    }
}

// ---------------------------------------------------------------------------
// kvsum over a 2-batch k chunk (local rows) + v (global rows at b0).
// Per (lb,h,chunk-of-512) block: K^T V 32x32 + sum_n K; fp32 atomics.
// ---------------------------------------------------------------------------
__global__ __launch_bounds__(256)
void kvsum_kernel(const u16* __restrict__ k, const u16* __restrict__ v,
                  float* __restrict__ kvsum, float* __restrict__ ksum, int b0)
{
    const int idx   = blockIdx.x;          // 128 = 2 batches * 8 heads * 8 chunks
    const int chunk = idx & 7;
    const int h     = (idx >> 3) & 7;
    const int lb    = idx >> 6;            // 0..1
    const int b     = b0 + lb;
    const int n0    = chunk * 512;
    __shared__ float ks[8][32];
    __shared__ float vs[8][32];
    const int tid  = threadIdx.x;
    const int lrow = tid >> 5, ld = tid & 31;
    const int d  = tid >> 3;
    const int e0 = (tid & 7) * 4;
    float acc[4] = {0.f, 0.f, 0.f, 0.f};
    float ksacc = 0.f;
    const u16* kb = k + (size_t)lb * 4096 * 256 + h * 32;   // local chunk rows
    const u16* vb = v + (size_t)b  * 4096 * 256 + h * 32;   // global rows
    for (int r0 = n0; r0 < n0 + 512; r0 += 8) {
        ks[lrow][ld] = b2f(kb[(size_t)(r0 + lrow) * 256 + ld]);
        vs[lrow][ld] = b2f(vb[(size_t)(r0 + lrow) * 256 + ld]);
        __syncthreads();
        #pragma unroll
        for (int r = 0; r < 8; ++r) {
            const float kd = ks[r][d];
            const float4 vv = *reinterpret_cast<const float4*>(&vs[r][e0]);
            acc[0] = fmaf(kd, vv.x, acc[0]);
            acc[1] = fmaf(kd, vv.y, acc[1]);
            acc[2] = fmaf(kd, vv.z, acc[2]);
            acc[3] = fmaf(kd, vv.w, acc[3]);
            if ((tid & 7) == 0) ksacc += kd;
        }
        __syncthreads();
    }
    float* kvp = kvsum + ((size_t)(b * 8 + h) * 32 + d) * 32 + e0;
    atomicAdd(&kvp[0], acc[0]);
    atomicAdd(&kvp[1], acc[1]);
    atomicAdd(&kvp[2], acc[2]);
    atomicAdd(&kvp[3], acc[3]);
    if ((tid & 7) == 0) atomicAdd(&ksum[(size_t)(b * 8 + h) * 32 + d], ksacc);
}

// ---------------------------------------------------------------------------
// attn IN-PLACE on qy: reads q tile into LDS first, then overwrites with y.
// y[b,n,h*32+e] = (q . kvmat[:,e]) / (q . kmean + eps)
// ---------------------------------------------------------------------------
__global__ __launch_bounds__(256)
void attn_kernel(u16* qy, const float* __restrict__ kvsum,
                 const float* __restrict__ ksum)
{
    __shared__ float kvs[8][32][32];
    __shared__ float km[8][32];
    __shared__ float qs[16][256];
    const int tid = threadIdx.x;
    const int b   = blockIdx.x >> 8;
    const int n0  = (blockIdx.x & 255) * 16;
    const float inv_n = 1.0f / 4096.0f;
    for (int i = tid; i < 8 * 32 * 32; i += 256)
        (&kvs[0][0][0])[i] = kvsum[(size_t)b * 8192 + i] * inv_n;
    (&km[0][0])[tid] = ksum[(size_t)b * 256 + tid] * inv_n;
    u16* qb = qy + ((size_t)b * 4096 + n0) * 256;
    #pragma unroll
    for (int t = 0; t < 16; ++t)
        qs[t][tid] = b2f(qb[(size_t)t * 256 + tid]);
    __syncthreads();                       // all q reads done before any write
    const int h = tid >> 5, e = tid & 31;
    for (int t = 0; t < 16; ++t) {
        float acc = 0.f, zd = 0.f;
        #pragma unroll
        for (int d = 0; d < 32; ++d) {
            const float qv = qs[t][h * 32 + d];
            acc = fmaf(qv, kvs[h][d][e], acc);
            zd  = fmaf(qv, km[h][d], zd);
        }
        qb[(size_t)t * 256 + tid] = f2b(acc / (zd + 1e-6f));
    }
}

// ---------------------------------------------------------------------------
// Depthwise 5x5 cross-correlation on v (B*h, 32ch, 64, 64), SAME pad,
// += into y with per-channel bias.
// ---------------------------------------------------------------------------
__global__ __launch_bounds__(256)
void conv_add_kernel(const u16* __restrict__ v, const void* __restrict__ w,
                     const void* __restrict__ bias, u16* __restrict__ y,
                     const int* __restrict__ flagp)
{
    const int f32 = *flagp;
    __shared__ float wl[800];
    __shared__ float bl[32];
    const int tid = threadIdx.x;
    for (int i = tid; i < 800; i += 256) wl[i] = ldv(w, i, f32);
    if (tid < 32) bl[tid] = ldv(bias, tid, f32);
    __syncthreads();
    const int b  = blockIdx.x >> 12;
    const int n  = blockIdx.x & 4095;
    const int y0 = n >> 6, x0 = n & 63;
    const int dc = tid & 31;
    const u16* vb = v + (size_t)b * 4096 * 256;
    float sum = 0.f;
    #pragma unroll
    for (int ky = 0; ky < 5; ++ky) {
        const int yy = y0 + ky - 2;
        if (yy < 0 || yy >= 64) continue;
        #pragma unroll
        for (int kx = 0; kx < 5; ++kx) {
            const int xx = x0 + kx - 2;
            if (xx < 0 || xx >= 64) continue;
            sum = fmaf(b2f(vb[(size_t)((yy << 6) + xx) * 256 + tid]),
                       wl[dc * 25 + ky * 5 + kx], sum);
        }
    }
    const size_t oi = ((size_t)b * 4096 + n) * 256 + tid;
    y[oi] = f2b(b2f(y[oi]) + sum + bl[dc]);
}

// ---------------------------------------------------------------------------
extern "C" void kernel_launch(void* const* d_in, const int* in_sizes, int n_in,
                              void* d_out, int out_size, void* d_ws, size_t ws_size,
                              hipStream_t stream)
{
    (void)in_sizes; (void)n_in; (void)out_size; (void)ws_size;
    const void* x   = d_in[0];
    const void* Wq  = d_in[1];
    const void* Wkv = d_in[2];
    const void* Wp  = d_in[3];
    const void* bp  = d_in[4];
    const void* sp  = d_in[5];
    const void* pe  = d_in[6];
    const void* dw  = d_in[7];
    const void* db  = d_in[8];
    u16* out = (u16*)d_out;            // actual store dtype chosen per flag

    // ws layout (total ~36.5 MB):
    //   [flag 64B][kvsm 512KB fp32][ksm 16KB fp32][qy 32MB bf16][kchunk 4MB bf16]
    float* wsf  = (float*)d_ws;
    int*   flag = (int*)d_ws;
    float* kvsm = wsf + 16;
    float* ksm  = kvsm + 131072;
    u16*   qy   = (u16*)(ksm + 4096);
    u16*   kch  = qy + (size_t)16777216;
    u16*   v    = (u16*)d_out;         // v (bf16, 32MB) parked in d_out;
                                       // dead before the final GEMM overwrites d_out

    hipMemsetAsync(kvsm, 0, (131072 + 4096) * sizeof(float), stream);
    detect_kernel<<<1, 64, 0, stream>>>(x, flag);

    dim3 blk(256);
    // q = x @ Wq  (full, 65536 rows)
    hipLaunchKernelGGL((gemm_k256<0>), dim3(4, 1024), blk, 0, stream,
                       x, Wq, qy, (u16*)nullptr, (const void*)nullptr, 256, 0, flag);
    focus_kernel<<<16384, blk, 0, stream>>>(qy, sp, flag);
    // k in 8 chunks of 2 batches (8192 rows): gemm -> focus -> kvsum
    for (int p = 0; p < 8; ++p) {
        hipLaunchKernelGGL((gemm_k256<1>), dim3(8, 128), blk, 0, stream,
                           x, Wkv, kch, v, pe, 512, p * 8192, flag);
        focus_kernel<<<2048, blk, 0, stream>>>(kch, sp, flag);
        kvsum_kernel<<<128, blk, 0, stream>>>(kch, v, kvsm, ksm, p * 2);
    }
    attn_kernel<<<4096, blk, 0, stream>>>(qy, kvsm, ksm);      // qy := y in-place
    conv_add_kernel<<<65536, blk, 0, stream>>>(v, dw, db, qy, flag);
    hipLaunchKernelGGL((gemm_k256<2>), dim3(4, 1024), blk, 0, stream,
                       qy, Wp, out, (u16*)nullptr, bp, 256, 0, flag);
}

// Round 7
// 875.910 us; speedup vs baseline: 1.5312x; 1.5312x over previous
//
#include <hip/hip_runtime.h>
#include <hip/hip_bf16.h>

typedef unsigned short u16;
using bf16_t = __hip_bfloat16;
typedef short short8 __attribute__((ext_vector_type(8)));
typedef float f32x4 __attribute__((ext_vector_type(4)));

__device__ __forceinline__ float b2f(u16 u) {
    return __uint_as_float((unsigned int)u << 16);
}
__device__ __forceinline__ u16 f2b(float f) {
    bf16_t h = __float2bfloat16(f);
    union { bf16_t h; u16 u; } cv; cv.h = h; return cv.u;
}
__device__ __forceinline__ float ldv(const void* p, size_t i, int f32) {
    return f32 ? ((const float*)p)[i] : b2f(((const u16*)p)[i]);
}

// ---------------------------------------------------------------------------
// Input-dtype detector (flag=1 -> fp32 inputs & fp32 output).
// ---------------------------------------------------------------------------
__global__ void detect_kernel(const void* __restrict__ x, int* __restrict__ flag)
{
    const int t = threadIdx.x;
    const u16 h = ((const u16*)x)[2 * t];
    const int e = (h >> 7) & 0xFF;
    const int plaus = (e >= 112 && e <= 133) ? 1 : 0;
    const unsigned long long m = __ballot(plaus);
    if (t == 0) flag[0] = (__popcll(m) < 32) ? 1 : 0;
}

// pe -> peb (bf16 always).
__global__ __launch_bounds__(256)
void pecvt_kernel(const void* __restrict__ pe, u16* __restrict__ peb,
                  const int* __restrict__ flagp)
{
    const size_t i = ((size_t)blockIdx.x * 256 + threadIdx.x) * 4;
    if (*flagp) {
        const float4 f = *reinterpret_cast<const float4*>((const float*)pe + i);
        ushort4 o; o.x = f2b(f.x); o.y = f2b(f.y); o.z = f2b(f.z); o.w = f2b(f.w);
        *reinterpret_cast<ushort4*>(peb + i) = o;
    } else {
        *reinterpret_cast<ushort4*>(peb + i) =
            *reinterpret_cast<const ushort4*>((const u16*)pe + i);
    }
}

// W[K x N] -> WT[N x K(=256)] bf16, LDS-tiled transpose.
__global__ __launch_bounds__(256)
void wtrans_kernel(const void* __restrict__ W, u16* __restrict__ WT, int N,
                   const int* __restrict__ flagp)
{
    const int f32 = *flagp;
    __shared__ float tile[32][33];
    const int tx = threadIdx.x & 31, ty = threadIdx.x >> 5;   // ty 0..7
    const int bx = blockIdx.x % (N >> 5);   // n tile
    const int by = blockIdx.x / (N >> 5);   // k tile
    #pragma unroll
    for (int r = 0; r < 4; ++r) {
        const int k = by * 32 + ty + r * 8;
        const int n = bx * 32 + tx;
        tile[ty + r * 8][tx] = ldv(W, (size_t)k * N + n, f32);
    }
    __syncthreads();
    #pragma unroll
    for (int r = 0; r < 4; ++r) {
        const int n2 = bx * 32 + ty + r * 8;
        const int k2 = by * 32 + tx;
        WT[(size_t)n2 * 256 + k2] = f2b(tile[tx][ty + r * 8]);
    }
}

// ---------------------------------------------------------------------------
// MFMA GEMM: O[rows x 256-or-512] = A[rows x 256] @ B. A is external x
// (fp32 or bf16, converted during staging) for MODE 0/1, internal bf16 for
// MODE 2. BT bf16 [n][k] (pre-transposed). 128x128 tile, BK=64, 4 waves
// (2x2), each wave 4x4 grid of 16x16x32 bf16 MFMA tiles. fp32 accum.
// MODE 0: O0(bf16=qy) = A@B
// MODE 1: col<256 -> kch(bf16, LOCAL rows) = A@B + peb; col>=256 -> v(bf16,
//         GLOBAL rows) = A@B
// MODE 2: out = A@B + bias; fp32 or bf16 store per flag.
// ---------------------------------------------------------------------------
template<int MODE>
__global__ __launch_bounds__(256)
void gemm_mfma(const void* __restrict__ Aany, const u16* __restrict__ Abf,
               const u16* __restrict__ BT,
               u16* __restrict__ O0, u16* __restrict__ O1,
               const void* __restrict__ extra, const u16* __restrict__ peb,
               int row_base, const int* __restrict__ flagp)
{
    const int f32 = *flagp;

    __shared__ u16 As[128 * 72];   // [m][k], stride 72 (pad 8: 16B-aligned rows)
    __shared__ u16 Bs[128 * 72];   // [n][k]

    const int tid  = threadIdx.x;
    const int row0 = blockIdx.y * 128;
    const int col0 = blockIdx.x * 128;

    const int lane = tid & 63;
    const int wv   = tid >> 6;
    const int wm   = (wv & 1) * 64;
    const int wn   = (wv >> 1) * 64;
    const int l15  = lane & 15;
    const int lq   = lane >> 4;

    const int sr = tid >> 1;              // staging row 0..127
    const int sk = (tid & 1) * 32;        // staging k-half

    f32x4 acc[4][4] = {};

    for (int k0 = 0; k0 < 256; k0 += 64) {
        // Stage A[row0+sr][k0+sk..+31] and BT[col0+sr][k0+sk..+31]:
        // 32 u16 per thread = 4 x uint4 (8 u16 each) at offsets 0,8,16,24.
        u16* al = &As[sr * 72 + sk];
        u16* bl = &Bs[sr * 72 + sk];
        const size_t arow = (size_t)(row_base + row0 + sr) * 256 + k0 + sk;
        if (MODE != 2 && f32) {
            // fp32 A: load 32 floats (8 x float4), convert to bf16.
            const float* ag = (const float*)Aany + arow;
            #pragma unroll
            for (int j = 0; j < 4; ++j) {
                const float4 f0 = *reinterpret_cast<const float4*>(ag + j * 8);
                const float4 f1 = *reinterpret_cast<const float4*>(ag + j * 8 + 4);
                ushort4 p0, p1;
                p0.x = f2b(f0.x); p0.y = f2b(f0.y); p0.z = f2b(f0.z); p0.w = f2b(f0.w);
                p1.x = f2b(f1.x); p1.y = f2b(f1.y); p1.z = f2b(f1.z); p1.w = f2b(f1.w);
                *reinterpret_cast<ushort4*>(al + j * 8)     = p0;
                *reinterpret_cast<ushort4*>(al + j * 8 + 4) = p1;
            }
        } else {
            const u16* ag = ((MODE == 2) ? Abf : (const u16*)Aany) + arow;
            #pragma unroll
            for (int j = 0; j < 4; ++j)
                *reinterpret_cast<uint4*>(al + j * 8) =
                    *reinterpret_cast<const uint4*>(ag + j * 8);
        }
        const u16* bg = BT + (size_t)(col0 + sr) * 256 + k0 + sk;
        #pragma unroll
        for (int j = 0; j < 4; ++j)
            *reinterpret_cast<uint4*>(bl + j * 8) =
                *reinterpret_cast<const uint4*>(bg + j * 8);
        __syncthreads();
        #pragma unroll
        for (int ks = 0; ks < 64; ks += 32) {
            short8 av[4], bvv[4];
            #pragma unroll
            for (int i = 0; i < 4; ++i)
                av[i] = *reinterpret_cast<const short8*>(
                    &As[(wm + i * 16 + l15) * 72 + ks + lq * 8]);
            #pragma unroll
            for (int j = 0; j < 4; ++j)
                bvv[j] = *reinterpret_cast<const short8*>(
                    &Bs[(wn + j * 16 + l15) * 72 + ks + lq * 8]);
            #pragma unroll
            for (int i = 0; i < 4; ++i)
                #pragma unroll
                for (int j = 0; j < 4; ++j)
                    acc[i][j] = __builtin_amdgcn_mfma_f32_16x16x32_bf16(
                        av[i], bvv[j], acc[i][j], 0, 0, 0);
        }
        __syncthreads();
    }

    // Epilogue. C/D layout: row=(lane>>4)*4+reg, col=lane&15 (m89-verified).
    #pragma unroll
    for (int i = 0; i < 4; ++i) {
        #pragma unroll
        for (int j = 0; j < 4; ++j) {
            const int gcol = col0 + wn + j * 16 + l15;
            #pragma unroll
            for (int rg = 0; rg < 4; ++rg) {
                const int lrow = row0 + wm + i * 16 + lq * 4 + rg;  // local row
                const float a = acc[i][j][rg];
                if (MODE == 0) {
                    O0[(size_t)lrow * 256 + gcol] = f2b(a);
                } else if (MODE == 1) {
                    if (col0 < 256) {
                        const int n = (row_base + lrow) & 4095;
                        O0[(size_t)lrow * 256 + gcol] =
                            f2b(a + b2f(peb[(size_t)n * 256 + gcol]));
                    } else {
                        O1[((size_t)row_base + lrow) * 256 + (gcol - 256)] = f2b(a);
                    }
                } else {
                    const float o = a + ldv(extra, gcol, f32);
                    if (f32) ((float*)O0)[(size_t)lrow * 256 + gcol] = o;
                    else     O0[(size_t)lrow * 256 + gcol] = f2b(o);
                }
            }
        }
    }
}

// ---------------------------------------------------------------------------
// Focus: t=(relu(t)+eps)/softplus(p); t := t^3 * ||t||/||t^3||. In-place bf16.
// ---------------------------------------------------------------------------
__global__ __launch_bounds__(256)
void focus_kernel(u16* __restrict__ buf, const void* __restrict__ scale_param,
                  const int* __restrict__ flagp)
{
    const int f32 = *flagp;
    __shared__ float ssc[256];
    const int tid = threadIdx.x;
    {
        const float p = ldv(scale_param, tid, f32);
        ssc[tid] = (p > 20.f) ? p : log1pf(expf(p));
    }
    __syncthreads();
    const int lane = tid & 63;
    const int wv   = tid >> 6;
    const size_t row = (size_t)blockIdx.x * 4 + wv;
    u16* t = buf + row * 256;
    float tv[4]; float s2 = 0.f, s6 = 0.f;
    #pragma unroll
    for (int i = 0; i < 4; ++i) {
        const int c = lane + i * 64;
        float x = b2f(t[c]);
        x = fmaxf(x, 0.f) + 1e-6f;
        x = x / ssc[c];
        tv[i] = x;
        const float x2 = x * x;
        s2 += x2;
        const float x3 = x2 * x;
        s6 += x3 * x3;
    }
    #pragma unroll
    for (int off = 32; off > 0; off >>= 1) {
        s2 += __shfl_xor(s2, off);
        s6 += __shfl_xor(s6, off);
    }
    const float ratio = sqrtf(s2 / s6);
    #pragma unroll
    for (int i = 0; i < 4; ++i) {
        const int c = lane + i * 64;
        const float x = tv[i];
        t[c] = f2b(x * x * x * ratio);
    }
}

// ---------------------------------------------------------------------------
// kvsum over a 2-batch k chunk (local rows) + v (global rows at b0).
// ---------------------------------------------------------------------------
__global__ __launch_bounds__(256)
void kvsum_kernel(const u16* __restrict__ k, const u16* __restrict__ v,
                  float* __restrict__ kvsum, float* __restrict__ ksum, int b0)
{
    const int idx   = blockIdx.x;
    const int chunk = idx & 7;
    const int h     = (idx >> 3) & 7;
    const int lb    = idx >> 6;
    const int b     = b0 + lb;
    const int n0    = chunk * 512;
    __shared__ float ks[8][32];
    __shared__ float vs[8][32];
    const int tid  = threadIdx.x;
    const int lrow = tid >> 5, ld = tid & 31;
    const int d  = tid >> 3;
    const int e0 = (tid & 7) * 4;
    float acc[4] = {0.f, 0.f, 0.f, 0.f};
    float ksacc = 0.f;
    const u16* kb = k + (size_t)lb * 4096 * 256 + h * 32;
    const u16* vb = v + (size_t)b  * 4096 * 256 + h * 32;
    for (int r0 = n0; r0 < n0 + 512; r0 += 8) {
        ks[lrow][ld] = b2f(kb[(size_t)(r0 + lrow) * 256 + ld]);
        vs[lrow][ld] = b2f(vb[(size_t)(r0 + lrow) * 256 + ld]);
        __syncthreads();
        #pragma unroll
        for (int r = 0; r < 8; ++r) {
            const float kd = ks[r][d];
            const float4 vv = *reinterpret_cast<const float4*>(&vs[r][e0]);
            acc[0] = fmaf(kd, vv.x, acc[0]);
            acc[1] = fmaf(kd, vv.y, acc[1]);
            acc[2] = fmaf(kd, vv.z, acc[2]);
            acc[3] = fmaf(kd, vv.w, acc[3]);
            if ((tid & 7) == 0) ksacc += kd;
        }
        __syncthreads();
    }
    float* kvp = kvsum + ((size_t)(b * 8 + h) * 32 + d) * 32 + e0;
    atomicAdd(&kvp[0], acc[0]);
    atomicAdd(&kvp[1], acc[1]);
    atomicAdd(&kvp[2], acc[2]);
    atomicAdd(&kvp[3], acc[3]);
    if ((tid & 7) == 0) atomicAdd(&ksum[(size_t)(b * 8 + h) * 32 + d], ksacc);
}

// ---------------------------------------------------------------------------
// attn IN-PLACE on qy.
// ---------------------------------------------------------------------------
__global__ __launch_bounds__(256)
void attn_kernel(u16* qy, const float* __restrict__ kvsum,
                 const float* __restrict__ ksum)
{
    __shared__ float kvs[8][32][32];
    __shared__ float km[8][32];
    __shared__ float qs[16][256];
    const int tid = threadIdx.x;
    const int b   = blockIdx.x >> 8;
    const int n0  = (blockIdx.x & 255) * 16;
    const float inv_n = 1.0f / 4096.0f;
    for (int i = tid; i < 8 * 32 * 32; i += 256)
        (&kvs[0][0][0])[i] = kvsum[(size_t)b * 8192 + i] * inv_n;
    (&km[0][0])[tid] = ksum[(size_t)b * 256 + tid] * inv_n;
    u16* qb = qy + ((size_t)b * 4096 + n0) * 256;
    #pragma unroll
    for (int t = 0; t < 16; ++t)
        qs[t][tid] = b2f(qb[(size_t)t * 256 + tid]);
    __syncthreads();
    const int h = tid >> 5, e = tid & 31;
    for (int t = 0; t < 16; ++t) {
        float acc = 0.f, zd = 0.f;
        #pragma unroll
        for (int d = 0; d < 32; ++d) {
            const float qv = qs[t][h * 32 + d];
            acc = fmaf(qv, kvs[h][d][e], acc);
            zd  = fmaf(qv, km[h][d], zd);
        }
        qb[(size_t)t * 256 + tid] = f2b(acc / (zd + 1e-6f));
    }
}

// ---------------------------------------------------------------------------
// Depthwise 5x5 conv, 4x4 pixel tile per thread (thread = channel).
// 8x8 register window: 4 loads/output vs 25. += into y with bias.
// ---------------------------------------------------------------------------
__global__ __launch_bounds__(256)
void conv_add_kernel(const u16* __restrict__ v, const void* __restrict__ w,
                     const void* __restrict__ bias, u16* __restrict__ y,
                     const int* __restrict__ flagp)
{
    const int f32 = *flagp;
    __shared__ float wl[800];
    __shared__ float bl[32];
    const int tid = threadIdx.x;
    for (int i = tid; i < 800; i += 256) wl[i] = ldv(w, i, f32);
    if (tid < 32) bl[tid] = ldv(bias, tid, f32);
    __syncthreads();
    const int bb = blockIdx.x >> 8;
    const int ty = (blockIdx.x >> 4) & 15;
    const int tx = blockIdx.x & 15;
    const int y0 = ty * 4, x0 = tx * 4;
    const int dc = tid & 31;
    float wreg[25];
    #pragma unroll
    for (int i = 0; i < 25; ++i) wreg[i] = wl[dc * 25 + i];
    const float bv = bl[dc];

    float vr[8][8];
    const u16* vb = v + (size_t)bb * 4096 * 256 + tid;
    #pragma unroll
    for (int iy = 0; iy < 8; ++iy) {
        const int yy = y0 + iy - 2;
        #pragma unroll
        for (int ix = 0; ix < 8; ++ix) {
            const int xx = x0 + ix - 2;
            vr[iy][ix] = (yy >= 0 && yy < 64 && xx >= 0 && xx < 64)
                       ? b2f(vb[(size_t)((yy << 6) + xx) * 256]) : 0.f;
        }
    }
    #pragma unroll
    for (int oy = 0; oy < 4; ++oy) {
        #pragma unroll
        for (int ox = 0; ox < 4; ++ox) {
            float s = 0.f;
            #pragma unroll
            for (int ky = 0; ky < 5; ++ky)
                #pragma unroll
                for (int kx = 0; kx < 5; ++kx)
                    s = fmaf(vr[oy + ky][ox + kx], wreg[ky * 5 + kx], s);
            const size_t oi = ((size_t)bb * 4096 + ((y0 + oy) << 6) + x0 + ox) * 256 + tid;
            y[oi] = f2b(b2f(y[oi]) + s + bv);
        }
    }
}

// ---------------------------------------------------------------------------
extern "C" void kernel_launch(void* const* d_in, const int* in_sizes, int n_in,
                              void* d_out, int out_size, void* d_ws, size_t ws_size,
                              hipStream_t stream)
{
    (void)in_sizes; (void)n_in; (void)out_size; (void)ws_size;
    const void* x   = d_in[0];
    const void* Wq  = d_in[1];
    const void* Wkv = d_in[2];
    const void* Wp  = d_in[3];
    const void* bp  = d_in[4];
    const void* sp  = d_in[5];
    const void* pe  = d_in[6];
    const void* dw  = d_in[7];
    const void* db  = d_in[8];

    // ws layout (~39 MB):
    // [flag 64B][kvsm 512K][ksm 16K][WqT 128K][WkvT 256K][WpT 128K][peb 2M]
    // [qy 32M][kch 4M]
    int*   flag = (int*)d_ws;
    float* kvsm = (float*)((char*)d_ws + 64);
    float* ksm  = kvsm + 131072;
    u16*   WqT  = (u16*)(ksm + 4096);
    u16*   WkvT = WqT + 65536;
    u16*   WpT  = WkvT + 131072;
    u16*   peb  = WpT + 65536;
    u16*   qy   = peb + 1048576;
    u16*   kch  = qy + (size_t)16777216;
    // v (bf16, 33.5 MB) parked at the START of d_out (d_out is 64 MB fp32 or
    // 33.5 MB bf16 — fits either way); dead before the final GEMM overwrites.
    u16*   v    = (u16*)d_out;

    hipMemsetAsync(kvsm, 0, (131072 + 4096) * sizeof(float), stream);
    detect_kernel<<<1, 64, 0, stream>>>(x, flag);
    pecvt_kernel<<<1024, 256, 0, stream>>>(pe, peb, flag);
    wtrans_kernel<<<64, 256, 0, stream>>>(Wq, WqT, 256, flag);
    wtrans_kernel<<<128, 256, 0, stream>>>(Wkv, WkvT, 512, flag);
    wtrans_kernel<<<64, 256, 0, stream>>>(Wp, WpT, 256, flag);

    // q = x @ Wq (65536 rows): grid (col tiles, row tiles)
    hipLaunchKernelGGL((gemm_mfma<0>), dim3(2, 512), dim3(256), 0, stream,
                       x, (const u16*)nullptr, WqT, qy, (u16*)nullptr,
                       (const void*)nullptr, (const u16*)nullptr, 0, flag);
    focus_kernel<<<16384, 256, 0, stream>>>(qy, sp, flag);
    // k/v in 8 chunks of 8192 rows: gemm -> focus(k) -> kvsum
    for (int p = 0; p < 8; ++p) {
        hipLaunchKernelGGL((gemm_mfma<1>), dim3(4, 64), dim3(256), 0, stream,
                           x, (const u16*)nullptr, WkvT, kch, v,
                           (const void*)nullptr, peb, p * 8192, flag);
        focus_kernel<<<2048, 256, 0, stream>>>(kch, sp, flag);
        kvsum_kernel<<<128, 256, 0, stream>>>(kch, v, kvsm, ksm, p * 2);
    }
    attn_kernel<<<4096, 256, 0, stream>>>(qy, kvsm, ksm);
    conv_add_kernel<<<4096, 256, 0, stream>>>(v, dw, db, qy, flag);
    hipLaunchKernelGGL((gemm_mfma<2>), dim3(2, 512), dim3(256), 0, stream,
                       (const void*)nullptr, qy, WpT, (u16*)d_out, (u16*)nullptr,
                       bp, (const u16*)nullptr, 0, flag);
}